// Round 13
// baseline (120.060 us; speedup 1.0000x reference)
//
#include <hip/hip_runtime.h>
#include <hip/hip_bf16.h>
#include <stdint.h>
#include <math.h>

#define NB 32
#define NF 512
#define NH 8
#define ND 64
#define NS 256
#define TOPK 51
#define STILE 16
#define LDSF 537   // swizzled row stride; OFF(f)=f+8*(f>>7)
#define NKPAD 52

__device__ __forceinline__ float wave_sum_f32(float v) {
#pragma unroll
  for (int o = 32; o > 0; o >>= 1) v += __shfl_xor(v, o, 64);
  return v;
}

__device__ __forceinline__ int lane_prefix(unsigned long long m) {
  return __builtin_amdgcn_mbcnt_hi((unsigned)(m >> 32),
         __builtin_amdgcn_mbcnt_lo((unsigned)m, 0u));
}

__device__ __forceinline__ unsigned f32key(float x) {
  unsigned b = __float_as_uint(x);
  return (b & 0x80000000u) ? ~b : (b | 0x80000000u);
}

// Bit-exact numpy pairwise_sum(n=512) on a swizzled LDS row.
// Element f at word OFF(f)=f+8*(f>>7); 128-block k contiguous at 136k.
// Chain (k,c): banks (8k+c+8m)%32 cover all 32 -> conflict-free.
// Direct `r += blk[...]` form — compiler pipelines the ds_reads (R9: explicit
// preload arrays go to scratch under the VGPR cap).
__device__ __forceinline__ float np_pairwise_sum_512(const float* __restrict__ row, int lane) {
  const int c2 = lane & 31;
  const int k  = c2 >> 3;
  const int c  = c2 & 7;
  const float* blk = row + 136 * k;
  float r = blk[c];
#pragma unroll
  for (int m = 1; m < 16; ++m) r += blk[c + 8 * m];   // exact sequential order
  float s = r + __shfl_xor(r, 1, 64);
  s = s + __shfl_xor(s, 2, 64);
  s = s + __shfl_xor(s, 4, 64);
  float u = s + __shfl_xor(s, 8, 64);
  u = u + __shfl_xor(u, 16, 64);
  return u;
}

// Per-(h,s): exact softplus(beta) + Gaussian-model bracket for the top-k key
// threshold. Bracket is a HEURISTIC (guarded in main kernel); beta is exact.
__global__ __launch_bounds__(256)
void prep_kernel(const float* __restrict__ bp, const float* __restrict__ alpha,
                 float* __restrict__ betaf, unsigned* __restrict__ klo,
                 unsigned* __restrict__ khi) {
  const int gid  = blockIdx.x * 256 + threadIdx.x;
  const int hs   = gid >> 6;
  const int lane = gid & 63;
  if (hs >= NH * NS) return;
  const float scalef = (float)0.04419417382415922;
  const float* ar = alpha + (size_t)hs * NF;
  float s1 = 0.f, s2 = 0.f;
#pragma unroll
  for (int j = 0; j < 8; ++j) {
    float v = ar[lane + 64 * j] * scalef;
    s1 += v; s2 = fmaf(v, v, s2);
  }
  s1 = wave_sum_f32(s1); s2 = wave_sum_f32(s2);
  const float mean = s1 * (1.f / 512.f);
  float var = s2 * (1.f / 512.f) - mean * mean;
  if (var < 0.f) var = 0.f;
  const double e = exp((double)bp[hs]);        // numpy softplus on f32 input
  const float beta = (float)log1p(e);
  const float sig  = sqrtf(var + beta * beta);
  const float that = fmaf(1.281552f, sig, mean);   // 90.04th pct (top 51/512)
  const float w    = 0.30f * sig;
  if (lane == 0) {
    betaf[hs] = beta;
    klo[hs] = f32key(that - w);
    khi[hs] = f32key(that + w);
  }
}

__global__ __launch_bounds__(1024, 8)   // VGPR<=64 -> 2 blocks (32 waves)/CU
void gating_attention_kernel(const float* __restrict__ vals,   // [B,F,H,D]
                             const float* __restrict__ dlg,    // [B,F,H,S]
                             const float* __restrict__ alpha,  // [H,S,F]
                             const float* __restrict__ betap,  // [H,S,1]
                             const float* __restrict__ betaf,  // [H*S] softplus (or null)
                             const unsigned* __restrict__ klo, // [H*S] bracket lo
                             const unsigned* __restrict__ khi, // [H*S] bracket hi
                             float* __restrict__ out)          // [B,S,H,D]
{
#pragma clang fp contract(off)       // numpy does mul THEN add; forbid fma fusion
  __shared__ float dl_t[STILE * LDSF];
  __shared__ uint2 pairs[STILE][NKPAD];

  const int blk  = blockIdx.x;       // bh in low 8 bits -> XCD = h (L2 locality)
  const int bh   = blk & 255;
  const int t    = blk >> 8;         // 0..15
  const int b    = bh >> 3;
  const int h    = bh & 7;
  const int s0   = t * STILE;
  const int tid  = threadIdx.x;
  const int w    = tid >> 6;
  const int lane = tid & 63;
  const float scalef = (float)0.04419417382415922;   // f32(1/sqrt(512))

  // ---- stage data_logits tile [16 s][512 f], transposed, full 64B lines ----
#pragma unroll
  for (int cc = 0; cc < 2; ++cc) {
    int i  = cc * 1024 + tid;         // 0..2047
    int f  = i >> 2;                  // 0..511
    int sg = (i & 3) << 2;            // 0,4,8,12
    int fo = f + ((f >> 7) << 3);
    const float4 v4 = *reinterpret_cast<const float4*>(
        dlg + ((((size_t)b * NF + f) * NH + h) * NS + (size_t)(s0 + sg)));
    dl_t[(sg + 0) * LDSF + fo] = v4.x;
    dl_t[(sg + 1) * LDSF + fo] = v4.y;
    dl_t[(sg + 2) * LDSF + fo] = v4.z;
    dl_t[(sg + 3) * LDSF + fo] = v4.w;
  }
  __syncthreads();

  const int s  = s0 + w;
  const int hs = h * NS + s;
  float* row = dl_t + w * LDSF;      // this wave's private swizzled row

  // lane->f mapping: f(g,jj) = 256*g + 4*lane + jj  (g=0,1; jj=0..3)
  const int fb0 = 4 * lane;
  const int off0 = fb0 + ((fb0 >> 7) << 3);
  const int fb1 = 256 + 4 * lane;
  const int off1 = fb1 + ((fb1 >> 7) << 3);

  const float4 a40 = *reinterpret_cast<const float4*>(
      alpha + ((size_t)hs) * NF + fb0);
  const float4 a41 = *reinterpret_cast<const float4*>(
      alpha + ((size_t)hs) * NF + fb1);
  const float4 x40 = *reinterpret_cast<const float4*>(row + off0);
  const float4 x41 = *reinterpret_cast<const float4*>(row + off1);

  float a[8] = {a40.x, a40.y, a40.z, a40.w, a41.x, a41.y, a41.z, a41.w};
  float x[8] = {x40.x, x40.y, x40.z, x40.w, x41.x, x41.y, x41.z, x41.w};

  // ---- mu: numpy-exact pairwise sum / 512 ----
  const float S1 = np_pairwise_sum_512(row, lane);
  const float mu = S1 * (1.0f / 512.0f);

  // ---- var: t=(x-mu); t*t; pairwise sum / 512 ----
  float tv[8];
#pragma unroll
  for (int j = 0; j < 8; ++j) tv[j] = x[j] - mu;
  *reinterpret_cast<float4*>(row + off0) =
      make_float4(tv[0]*tv[0], tv[1]*tv[1], tv[2]*tv[2], tv[3]*tv[3]);
  *reinterpret_cast<float4*>(row + off1) =
      make_float4(tv[4]*tv[4], tv[5]*tv[5], tv[6]*tv[6], tv[7]*tv[7]);
  const float S2  = np_pairwise_sum_512(row, lane);
  const float var = S2 * (1.0f / 512.0f);
  const float stdv = sqrtf(var + 1e-6f) + 1e-6f;   // IEEE f32 sqrt (numpy op)

  // ---- beta ----
  float beta;
  if (betaf) beta = betaf[hs];
  else { double e = exp((double)betap[hs]); beta = (float)log1p(e); }

  // ---- logits: numpy f32 op order; divide via uniform f64 reciprocal ----
  const double rd = 1.0 / (double)stdv;
  float lg[8];
  unsigned key[8];
#pragma unroll
  for (int j = 0; j < 8; ++j) {
    float z  = (float)((double)tv[j] * rd);   // == IEEE f32 div (2^-29 corner aside)
    float m  = beta * z;
    float af = a[j] * scalef;
    float l  = af + m;
    lg[j] = l;
    key[j] = f32key(l);
  }

  auto countGE = [&key](unsigned thr) -> int {
    int c = 0;
#pragma unroll
    for (int j = 0; j < 8; ++j) c += __popcll(__ballot(key[j] >= thr));
    return c;
  };

  // ---- bracket init (precomputed model, or min/max fallback) ----
  unsigned lo, hi;
  if (klo) {
    lo = klo[hs]; hi = khi[hs];
    if (hi <= lo) hi = lo + 1;
  } else {
    unsigned kmax = key[0], kmin = key[0];
#pragma unroll
    for (int j = 1; j < 8; ++j) {
      kmax = key[j] > kmax ? key[j] : kmax;
      kmin = key[j] < kmin ? key[j] : kmin;
    }
#pragma unroll
    for (int o = 32; o > 0; o >>= 1) {
      unsigned om = (unsigned)__shfl_xor((int)kmax, o, 64);
      unsigned on = (unsigned)__shfl_xor((int)kmin, o, 64);
      kmax = om > kmax ? om : kmax;
      kmin = on < kmin ? on : kmin;
    }
    lo = kmin; hi = kmax;
  }

  // ---- guarded exact bisection: T = largest key with count(>=T) >= TOPK ----
  int cl = countGE(lo);
  unsigned step = hi - lo;
  while (cl < TOPK) {                 // bracket entirely above threshold (rare)
    hi = lo;
    lo = (lo >= step) ? (lo - step) : 0u;
    step <<= 1;
    cl = countGE(lo);
  }
  unsigned T; int cnt;
  if (cl == TOPK) { T = lo; cnt = cl; }
  else {
    int ch = countGE(hi);
    while (ch >= TOPK && hi != 0xFFFFFFFFu) {   // bracket below threshold (rare)
      lo = hi; cl = ch;
      unsigned nh = hi + step;
      if (nh < hi) nh = 0xFFFFFFFFu;
      hi = nh; step <<= 1;
      ch = countGE(hi);
    }
    if (ch >= TOPK) { T = hi; cnt = ch; }
    else {
      while (lo < hi) {
        unsigned mid = hi - ((hi - lo) >> 1);
        int cm = countGE(mid);
        if (cm >= TOPK) { lo = mid; cl = cm; if (cm == TOPK) break; }
        else hi = mid - 1;
      }
      T = lo; cnt = cl;
    }
  }
  const bool exact = (cnt == TOPK);

  // ---- keep mask; tie resolution only when needed ----
  bool keep[8];
  if (exact) {
#pragma unroll
    for (int j = 0; j < 8; ++j) keep[j] = (key[j] >= T);
  } else {
    int g = 0;
#pragma unroll
    for (int j = 0; j < 8; ++j) g += __popcll(__ballot(key[j] > T));
    const int need = TOPK - g;
    int cumt = 0;
#pragma unroll
    for (int j = 0; j < 8; ++j) {
      unsigned long long meq = __ballot(key[j] == T);
      int tr = cumt + lane_prefix(meq);
      cumt += __popcll(meq);
      keep[j] = (key[j] > T) || ((key[j] == T) && (tr < need));
    }
  }

  unsigned tb = (T & 0x80000000u) ? (T ^ 0x80000000u) : ~T;
  const float thrf = __uint_as_float(tb);

  // ---- softmax numerators over kept set ----
  float p[8];
  float zs = 0.0f;
#pragma unroll
  for (int j = 0; j < 8; ++j) {
    float e = keep[j] ? __expf(lg[j] - thrf) : 0.0f;
    p[j] = e;
    zs += e;
  }
  // zs wave-reduction deferred past the gather issue (latency overlap).

  // ---- compact kept (byte-offset, p) pairs into LDS ----
  int base = 0;
#pragma unroll
  for (int j = 0; j < 8; ++j) {
    unsigned long long mk = __ballot(keep[j]);
    int idx = base + lane_prefix(mk);
    if (keep[j]) {
      unsigned f = (unsigned)(((j >> 2) << 8) + 4 * lane + (j & 3));
      pairs[w][idx] = make_uint2(f << 11, __float_as_uint(p[j]));  // f*NH*ND*4 bytes
    }
    base += __popcll(mk);
  }
  if (lane == TOPK) pairs[w][TOPK] = make_uint2(0u, 0u);  // single pad slot

  // ---- sparse PV gather: 64-lane rows, 4 accumulators, saddr addressing ----
  // e.x/e.y are wave-uniform; readfirstlane moves them to SGPRs so the load
  // becomes saddr-form (scalar add on SALU) and p an SGPR operand to the FMA.
  const char* vbase = (const char*)(vals + (((size_t)b * NF) * NH + h) * ND) + 4 * lane;
  float acc0 = 0.0f, acc1 = 0.0f, acc2 = 0.0f, acc3 = 0.0f;
  for (int k0 = 0; k0 < NKPAD; k0 += 4) {
    const uint2 e0 = pairs[w][k0 + 0];
    const uint2 e1 = pairs[w][k0 + 1];
    const uint2 e2 = pairs[w][k0 + 2];
    const uint2 e3 = pairs[w][k0 + 3];
    const unsigned o0 = __builtin_amdgcn_readfirstlane(e0.x);
    const unsigned o1 = __builtin_amdgcn_readfirstlane(e1.x);
    const unsigned o2 = __builtin_amdgcn_readfirstlane(e2.x);
    const unsigned o3 = __builtin_amdgcn_readfirstlane(e3.x);
    const float p0 = __uint_as_float(__builtin_amdgcn_readfirstlane(e0.y));
    const float p1 = __uint_as_float(__builtin_amdgcn_readfirstlane(e1.y));
    const float p2 = __uint_as_float(__builtin_amdgcn_readfirstlane(e2.y));
    const float p3 = __uint_as_float(__builtin_amdgcn_readfirstlane(e3.y));
    const float v0 = *(const float*)(vbase + o0);
    const float v1 = *(const float*)(vbase + o1);
    const float v2 = *(const float*)(vbase + o2);
    const float v3 = *(const float*)(vbase + o3);
    acc0 = fmaf(p0, v0, acc0);
    acc1 = fmaf(p1, v1, acc1);
    acc2 = fmaf(p2, v2, acc2);
    acc3 = fmaf(p3, v3, acc3);
  }
  const float acc = (acc0 + acc1) + (acc2 + acc3);

  // ---- deferred softmax denominator (overlaps gather latency) ----
  zs = wave_sum_f32(zs);
  const float rz = 1.0f / zs;

  out[(((size_t)b * NS + s) * NH + h) * ND + lane] = acc * rz;
}

extern "C" void kernel_launch(void* const* d_in, const int* in_sizes, int n_in,
                              void* d_out, int out_size, void* d_ws, size_t ws_size,
                              hipStream_t stream) {
  const float* vals  = (const float*)d_in[0];
  const float* dlg   = (const float*)d_in[1];
  const float* alpha = (const float*)d_in[2];
  const float* betap = (const float*)d_in[3];
  float* out = (float*)d_out;

  float* betaf = nullptr; unsigned* klo = nullptr; unsigned* khi = nullptr;
  const size_t need = (size_t)(NH * NS) * 12;   // beta + klo + khi
  if (ws_size >= need) {
    betaf = (float*)d_ws;
    klo   = (unsigned*)((char*)d_ws + (size_t)(NH * NS) * 4);
    khi   = (unsigned*)((char*)d_ws + (size_t)(NH * NS) * 8);
    prep_kernel<<<(NH * NS * 64) / 256, 256, 0, stream>>>(betap, alpha, betaf, klo, khi);
  }

  dim3 grid(NB * NH * (NS / STILE));   // 4096 blocks: one per (b,h,16-row tile)
  dim3 block(1024);
  gating_attention_kernel<<<grid, block, 0, stream>>>(vals, dlg, alpha, betap,
                                                      betaf, klo, khi, out);
}

// Round 14
// 106.804 us; speedup vs baseline: 1.1241x; 1.1241x over previous
//
#include <hip/hip_runtime.h>
#include <hip/hip_bf16.h>
#include <stdint.h>
#include <math.h>

#define NB 32
#define NF 512
#define NH 8
#define ND 64
#define NS 256
#define TOPK 51
#define STILE 16
#define LDSF 537   // swizzled row stride; OFF(f)=f+8*(f>>7)

__device__ __forceinline__ float wave_sum_f32(float v) {
#pragma unroll
  for (int o = 32; o > 0; o >>= 1) v += __shfl_xor(v, o, 64);
  return v;
}

__device__ __forceinline__ int lane_prefix(unsigned long long m) {
  return __builtin_amdgcn_mbcnt_hi((unsigned)(m >> 32),
         __builtin_amdgcn_mbcnt_lo((unsigned)m, 0u));
}

__device__ __forceinline__ unsigned f32key(float x) {
  unsigned b = __float_as_uint(x);
  return (b & 0x80000000u) ? ~b : (b | 0x80000000u);
}

// Bit-exact numpy pairwise_sum(n=512) on a swizzled LDS row.
// Element f at word OFF(f)=f+8*(f>>7); 128-block k contiguous at 136k.
// Chain (k,c): banks (8k+c+8m)%32 cover all 32 -> conflict-free.
__device__ __forceinline__ float np_pairwise_sum_512(const float* __restrict__ row, int lane) {
  const int c2 = lane & 31;
  const int k  = c2 >> 3;
  const int c  = c2 & 7;
  const float* blk = row + 136 * k;
  float r = blk[c];
#pragma unroll
  for (int m = 1; m < 16; ++m) r += blk[c + 8 * m];   // exact sequential order
  float s = r + __shfl_xor(r, 1, 64);
  s = s + __shfl_xor(s, 2, 64);
  s = s + __shfl_xor(s, 4, 64);
  float u = s + __shfl_xor(s, 8, 64);
  u = u + __shfl_xor(u, 16, 64);
  return u;
}

// Per-(h,s): exact softplus(beta) + Gaussian-model bracket for the top-k key
// threshold. Bracket is a HEURISTIC (guarded in the main kernel); beta is exact.
__global__ __launch_bounds__(256)
void prep_kernel(const float* __restrict__ bp, const float* __restrict__ alpha,
                 float* __restrict__ betaf, unsigned* __restrict__ klo,
                 unsigned* __restrict__ khi) {
  const int gid  = blockIdx.x * 256 + threadIdx.x;
  const int hs   = gid >> 6;
  const int lane = gid & 63;
  if (hs >= NH * NS) return;
  const float scalef = (float)0.04419417382415922;
  const float* ar = alpha + (size_t)hs * NF;
  float s1 = 0.f, s2 = 0.f;
#pragma unroll
  for (int j = 0; j < 8; ++j) {
    float v = ar[lane + 64 * j] * scalef;
    s1 += v; s2 = fmaf(v, v, s2);
  }
  s1 = wave_sum_f32(s1); s2 = wave_sum_f32(s2);
  const float mean = s1 * (1.f / 512.f);
  float var = s2 * (1.f / 512.f) - mean * mean;
  if (var < 0.f) var = 0.f;
  const double e = exp((double)bp[hs]);        // numpy softplus on f32 input
  const float beta = (float)log1p(e);
  // logits = a*scale + beta*z, z ~ empirical N(0,1) -> sigma_l^2 = var_a + beta^2
  const float sig  = sqrtf(var + beta * beta);
  const float that = fmaf(1.281552f, sig, mean);   // 90.04th pct (top 51/512)
  const float w    = 0.30f * sig;                  // ~4 sd of quantile noise
  if (lane == 0) {
    betaf[hs] = beta;
    klo[hs] = f32key(that - w);
    khi[hs] = f32key(that + w);
  }
}

__global__ __launch_bounds__(1024, 8)   // VGPR<=64 -> 2 blocks (32 waves)/CU
void gating_attention_kernel(const float* __restrict__ vals,   // [B,F,H,D]
                             const float* __restrict__ dlg,    // [B,F,H,S]
                             const float* __restrict__ alpha,  // [H,S,F]
                             const float* __restrict__ betap,  // [H,S,1]
                             const float* __restrict__ betaf,  // [H*S] softplus (or null)
                             const unsigned* __restrict__ klo, // [H*S] bracket lo (or null)
                             const unsigned* __restrict__ khi, // [H*S] bracket hi (or null)
                             float* __restrict__ out)          // [B,S,H,D]
{
#pragma clang fp contract(off)       // numpy does mul THEN add; forbid fma fusion
  __shared__ float dl_t[STILE * LDSF];
  __shared__ uint2 pairs[STILE][64];

  const int blk  = blockIdx.x;       // bh in low 8 bits -> XCD = h (L2 locality)
  const int bh   = blk & 255;
  const int t    = blk >> 8;         // 0..15
  const int b    = bh >> 3;
  const int h    = bh & 7;
  const int s0   = t * STILE;
  const int tid  = threadIdx.x;
  const int w    = tid >> 6;
  const int lane = tid & 63;
  const float scalef = (float)0.04419417382415922;   // f32(1/sqrt(512))

  // ---- stage data_logits tile [16 s][512 f], transposed, full 64B lines ----
#pragma unroll
  for (int cc = 0; cc < 2; ++cc) {
    int i  = cc * 1024 + tid;         // 0..2047
    int f  = i >> 2;                  // 0..511
    int sg = (i & 3) << 2;            // 0,4,8,12
    int fo = f + ((f >> 7) << 3);
    const float4 v4 = *reinterpret_cast<const float4*>(
        dlg + ((((size_t)b * NF + f) * NH + h) * NS + (size_t)(s0 + sg)));
    dl_t[(sg + 0) * LDSF + fo] = v4.x;
    dl_t[(sg + 1) * LDSF + fo] = v4.y;
    dl_t[(sg + 2) * LDSF + fo] = v4.z;
    dl_t[(sg + 3) * LDSF + fo] = v4.w;
  }
  __syncthreads();

  const int s  = s0 + w;
  const int hs = h * NS + s;
  float* row = dl_t + w * LDSF;      // this wave's private swizzled row

  // lane->f mapping: f(g,jj) = 256*g + 4*lane + jj  (g=0,1; jj=0..3)
  const int fb0 = 4 * lane;
  const int off0 = fb0 + ((fb0 >> 7) << 3);
  const int fb1 = 256 + 4 * lane;
  const int off1 = fb1 + ((fb1 >> 7) << 3);

  const float4 a40 = *reinterpret_cast<const float4*>(
      alpha + ((size_t)hs) * NF + fb0);
  const float4 a41 = *reinterpret_cast<const float4*>(
      alpha + ((size_t)hs) * NF + fb1);
  const float4 x40 = *reinterpret_cast<const float4*>(row + off0);
  const float4 x41 = *reinterpret_cast<const float4*>(row + off1);

  float a[8] = {a40.x, a40.y, a40.z, a40.w, a41.x, a41.y, a41.z, a41.w};
  float x[8] = {x40.x, x40.y, x40.z, x40.w, x41.x, x41.y, x41.z, x41.w};

  // ---- mu: numpy-exact pairwise sum / 512 ----
  const float S1 = np_pairwise_sum_512(row, lane);
  const float mu = S1 * (1.0f / 512.0f);

  // ---- var: t=(x-mu); t*t; pairwise sum / 512 ----
  float tv[8];
#pragma unroll
  for (int j = 0; j < 8; ++j) tv[j] = x[j] - mu;
  *reinterpret_cast<float4*>(row + off0) =
      make_float4(tv[0]*tv[0], tv[1]*tv[1], tv[2]*tv[2], tv[3]*tv[3]);
  *reinterpret_cast<float4*>(row + off1) =
      make_float4(tv[4]*tv[4], tv[5]*tv[5], tv[6]*tv[6], tv[7]*tv[7]);
  const float S2  = np_pairwise_sum_512(row, lane);
  const float var = S2 * (1.0f / 512.0f);
  const float stdv = sqrtf(var + 1e-6f) + 1e-6f;   // IEEE f32 sqrt (numpy op)

  // ---- beta ----
  float beta;
  if (betaf) beta = betaf[hs];
  else { double e = exp((double)betap[hs]); beta = (float)log1p(e); }

  // ---- logits: numpy f32 op order; divide via uniform f64 reciprocal ----
  const double rd = 1.0 / (double)stdv;
  float lg[8];
  unsigned key[8];
#pragma unroll
  for (int j = 0; j < 8; ++j) {
    float z  = (float)((double)tv[j] * rd);   // == IEEE f32 div (2^-29 corner aside)
    float m  = beta * z;
    float af = a[j] * scalef;
    float l  = af + m;
    lg[j] = l;
    key[j] = f32key(l);
  }

  auto countGE = [&key](unsigned thr) -> int {
    int c = 0;
#pragma unroll
    for (int j = 0; j < 8; ++j) c += __popcll(__ballot(key[j] >= thr));
    return c;
  };

  // ---- bracket init (precomputed model, or min/max fallback) ----
  unsigned lo, hi;
  if (klo) {
    lo = klo[hs]; hi = khi[hs];
    if (hi <= lo) hi = lo + 1;
  } else {
    unsigned kmax = key[0], kmin = key[0];
#pragma unroll
    for (int j = 1; j < 8; ++j) {
      kmax = key[j] > kmax ? key[j] : kmax;
      kmin = key[j] < kmin ? key[j] : kmin;
    }
#pragma unroll
    for (int o = 32; o > 0; o >>= 1) {
      unsigned om = (unsigned)__shfl_xor((int)kmax, o, 64);
      unsigned on = (unsigned)__shfl_xor((int)kmin, o, 64);
      kmax = om > kmax ? om : kmax;
      kmin = on < kmin ? on : kmin;
    }
    lo = kmin; hi = kmax;
  }

  // ---- guarded exact bisection: T = largest key with count(>=T) >= TOPK ----
  int cl = countGE(lo);
  unsigned step = hi - lo;
  while (cl < TOPK) {                 // bracket entirely above threshold (rare)
    hi = lo;
    lo = (lo >= step) ? (lo - step) : 0u;
    step <<= 1;
    cl = countGE(lo);
  }
  unsigned T; int cnt;
  if (cl == TOPK) { T = lo; cnt = cl; }
  else {
    int ch = countGE(hi);
    while (ch >= TOPK && hi != 0xFFFFFFFFu) {   // bracket below threshold (rare)
      lo = hi; cl = ch;
      unsigned nh = hi + step;
      if (nh < hi) nh = 0xFFFFFFFFu;
      hi = nh; step <<= 1;
      ch = countGE(hi);
    }
    if (ch >= TOPK) { T = hi; cnt = ch; }
    else {
      while (lo < hi) {
        unsigned mid = hi - ((hi - lo) >> 1);
        int cm = countGE(mid);
        if (cm >= TOPK) { lo = mid; cl = cm; if (cm == TOPK) break; }
        else hi = mid - 1;
      }
      T = lo; cnt = cl;
    }
  }
  const bool exact = (cnt == TOPK);

  // ---- keep mask; tie resolution only when needed ----
  bool keep[8];
  if (exact) {
#pragma unroll
    for (int j = 0; j < 8; ++j) keep[j] = (key[j] >= T);
  } else {
    int g = 0;
#pragma unroll
    for (int j = 0; j < 8; ++j) g += __popcll(__ballot(key[j] > T));
    const int need = TOPK - g;
    int cumt = 0;
#pragma unroll
    for (int j = 0; j < 8; ++j) {
      unsigned long long meq = __ballot(key[j] == T);
      int tr = cumt + lane_prefix(meq);
      cumt += __popcll(meq);
      keep[j] = (key[j] > T) || ((key[j] == T) && (tr < need));
    }
  }

  unsigned tb = (T & 0x80000000u) ? (T ^ 0x80000000u) : ~T;
  const float thrf = __uint_as_float(tb);

  // ---- softmax numerators over kept set ----
  float p[8];
  float zs = 0.0f;
#pragma unroll
  for (int j = 0; j < 8; ++j) {
    float e = keep[j] ? __expf(lg[j] - thrf) : 0.0f;
    p[j] = e;
    zs += e;
  }
  zs = wave_sum_f32(zs);
  const float rz = 1.0f / zs;

  // ---- compact kept (byte-offset, p) pairs into LDS ----
  int base = 0;
#pragma unroll
  for (int j = 0; j < 8; ++j) {
    unsigned long long mk = __ballot(keep[j]);
    int idx = base + lane_prefix(mk);
    if (keep[j]) {
      unsigned f = (unsigned)(((j >> 2) << 8) + 4 * lane + (j & 3));
      pairs[w][idx] = make_uint2(f << 11, __float_as_uint(p[j]));  // f*NH*ND*4 bytes
    }
    base += __popcll(mk);
  }
  if (lane == TOPK) pairs[w][TOPK] = make_uint2(0u, 0u);  // single pad slot
  const int nk = (TOPK + 3) & ~3;    // 52

  // ---- sparse PV gather: uniform base + 32-bit byte offsets, 4 accumulators ----
  const char* vbase = (const char*)(vals + (((size_t)b * NF) * NH + h) * ND) + 4 * lane;
  float acc0 = 0.0f, acc1 = 0.0f, acc2 = 0.0f, acc3 = 0.0f;
  for (int k0 = 0; k0 < nk; k0 += 4) {
    uint2 e0 = pairs[w][k0 + 0];
    uint2 e1 = pairs[w][k0 + 1];
    uint2 e2 = pairs[w][k0 + 2];
    uint2 e3 = pairs[w][k0 + 3];
    float v0 = *(const float*)(vbase + e0.x);
    float v1 = *(const float*)(vbase + e1.x);
    float v2 = *(const float*)(vbase + e2.x);
    float v3 = *(const float*)(vbase + e3.x);
    acc0 = fmaf(__uint_as_float(e0.y), v0, acc0);
    acc1 = fmaf(__uint_as_float(e1.y), v1, acc1);
    acc2 = fmaf(__uint_as_float(e2.y), v2, acc2);
    acc3 = fmaf(__uint_as_float(e3.y), v3, acc3);
  }
  const float acc = (acc0 + acc1) + (acc2 + acc3);

  out[(((size_t)b * NS + s) * NH + h) * ND + lane] = acc * rz;
}

extern "C" void kernel_launch(void* const* d_in, const int* in_sizes, int n_in,
                              void* d_out, int out_size, void* d_ws, size_t ws_size,
                              hipStream_t stream) {
  const float* vals  = (const float*)d_in[0];
  const float* dlg   = (const float*)d_in[1];
  const float* alpha = (const float*)d_in[2];
  const float* betap = (const float*)d_in[3];
  float* out = (float*)d_out;

  float* betaf = nullptr; unsigned* klo = nullptr; unsigned* khi = nullptr;
  const size_t need = (size_t)(NH * NS) * 12;   // beta + klo + khi
  if (ws_size >= need) {
    betaf = (float*)d_ws;
    klo   = (unsigned*)((char*)d_ws + (size_t)(NH * NS) * 4);
    khi   = (unsigned*)((char*)d_ws + (size_t)(NH * NS) * 8);
    prep_kernel<<<(NH * NS * 64) / 256, 256, 0, stream>>>(betap, alpha, betaf, klo, khi);
  }

  dim3 grid(NB * NH * (NS / STILE));   // 4096 blocks: one per (b,h,16-row tile)
  dim3 block(1024);
  gating_attention_kernel<<<grid, block, 0, stream>>>(vals, dlg, alpha, betap,
                                                      betaf, klo, khi, out);
}